// Round 3
// baseline (301.299 us; speedup 1.0000x reference)
//
#include <hip/hip_runtime.h>
#include <hip/hip_bf16.h>

#define SEQ 2048
#define DMODEL 2048
#define NHEAD 8
#define DHEAD 256

typedef _Float16 v8h __attribute__((ext_vector_type(8)));
typedef unsigned short v8u __attribute__((ext_vector_type(8)));
typedef float v4f __attribute__((ext_vector_type(4)));

__device__ __forceinline__ float b2f(unsigned short s) {
    return __uint_as_float(((unsigned)s) << 16);
}
__device__ __forceinline__ unsigned short f2b(float f) {
    unsigned u = __float_as_uint(f);
    u += 0x7fffu + ((u >> 16) & 1u);   // RNE
    return (unsigned short)(u >> 16);
}
__device__ __forceinline__ unsigned short f2h(float f) {
    _Float16 h = (_Float16)f;
    return __builtin_bit_cast(unsigned short, h);
}
__device__ __forceinline__ float h2f(unsigned short s) {
    return (float)__builtin_bit_cast(_Float16, s);
}

// ---------------------------------------------------------------- detect dtype
__global__ __launch_bounds__(256) void k_detect(const unsigned short* q, int* flag) {
    __shared__ int cnt;
    if (threadIdx.x == 0) cnt = 0;
    __syncthreads();
    int wild = 0;
    for (int i = threadIdx.x; i < 2048; i += 256) {
        float x = b2f(q[i]);
        float ax = fabsf(x);
        if (!(ax <= 100.0f) || (x != 0.0f && ax < 1e-6f)) wild++;
    }
    atomicAdd(&cnt, wild);
    __syncthreads();
    if (threadIdx.x == 0) *flag = (cnt < 256) ? 1 : 0;  // 1 = bf16, 0 = f32
}

// ----------------------------------------------- convert q, k -> fp16
__global__ __launch_bounds__(256) void k_cvt_qk(const void* q, const void* k,
                                                const int* flag,
                                                unsigned short* qb, unsigned short* kb) {
    int bf = *(volatile const int*)flag;
    size_t i0 = ((size_t)blockIdx.x * 256 + threadIdx.x) * 8;
    v8u oq, ok;
    if (bf) {
        v8u uq = *(const v8u*)((const unsigned short*)q + i0);
        v8u uk = *(const v8u*)((const unsigned short*)k + i0);
#pragma unroll
        for (int j = 0; j < 8; j++) {
            oq[j] = f2h(b2f(uq[j]));
            ok[j] = f2h(b2f(uk[j]));
        }
    } else {
        const float* qf = (const float*)q;
        const float* kf = (const float*)k;
#pragma unroll
        for (int j = 0; j < 8; j++) {
            oq[j] = f2h(qf[i0 + j]);
            ok[j] = f2h(kf[i0 + j]);
        }
    }
    *(v8u*)(qb + i0) = oq;
    *(v8u*)(kb + i0) = ok;
}

// ----------------------------------------------------------- out_weight -> f32
__global__ __launch_bounds__(256) void k_cvt_gw(const void* ow, const int* flag, float* gw) {
    int bf = *(volatile const int*)flag;
    int i = blockIdx.x * 256 + threadIdx.x;
    gw[i] = bf ? b2f(((const unsigned short*)ow)[i]) : ((const float*)ow)[i];
}

// ------------------------------------------- v -> vT[h][d][s] fp16 (transposed)
__global__ __launch_bounds__(256) void k_tr_v(const void* v, const int* flag,
                                              unsigned short* vT) {
    __shared__ unsigned short tile[64][72];
    int bf = *(volatile const int*)flag;
    int s0 = blockIdx.x * 64, d0 = blockIdx.y * 64;
    int r = threadIdx.x >> 2, c0 = (threadIdx.x & 3) * 16;
    size_t base = (size_t)(s0 + r) * DMODEL + d0 + c0;
    if (bf) {
        const unsigned short* vp = (const unsigned short*)v;
        v8u a = *(const v8u*)(vp + base);
        v8u b = *(const v8u*)(vp + base + 8);
#pragma unroll
        for (int j = 0; j < 8; j++) { tile[r][c0 + j] = f2h(b2f(a[j])); tile[r][c0 + 8 + j] = f2h(b2f(b[j])); }
    } else {
        const float* vp = (const float*)v;
#pragma unroll
        for (int j = 0; j < 16; j++) tile[r][c0 + j] = f2h(vp[base + j]);
    }
    __syncthreads();
    int dr = threadIdx.x >> 2, sc0 = (threadIdx.x & 3) * 16;
    v8u o0, o1;
#pragma unroll
    for (int j = 0; j < 8; j++) { o0[j] = tile[sc0 + j][dr]; o1[j] = tile[sc0 + 8 + j][dr]; }
    int head = d0 >> 8;
    int dh = (d0 & 255) + dr;
    size_t ob = ((size_t)head * DHEAD + dh) * SEQ + s0 + sc0;
    *(v8u*)(vT + ob) = o0;
    *(v8u*)(vT + ob + 8) = o1;
}

// --------------------------------------------- gate pre-activations (f32, no bias)
__global__ __launch_bounds__(256) void k_gates(const void* q, const void* k, const void* v,
                                               const void* igk, const void* fgk,
                                               const int* flag, float* ipre, float* fpre) {
    __shared__ float x_lds[32][68];
    int bf = *(volatile const int*)flag;
    int s0 = blockIdx.x * 32;
    int c  = blockIdx.y;
    int tid = threadIdx.x;
    int sl = tid >> 3, hh = tid & 7;
    int rr = tid >> 3, j0 = (tid & 7) * 8;
    float accI = 0.f, accF = 0.f;
    for (int wd = 0; wd < 12; ++wd) {
        int gd0 = c * 768 + wd * 64;
        const void* src; int off;
        if (gd0 < 2048)      { src = q; off = gd0; }
        else if (gd0 < 4096) { src = k; off = gd0 - 2048; }
        else                 { src = v; off = gd0 - 4096; }
        __syncthreads();
        size_t base = (size_t)(s0 + rr) * DMODEL + off + j0;
        if (bf) {
            const unsigned short* sp = (const unsigned short*)src;
            v8u a = *(const v8u*)(sp + base);
#pragma unroll
            for (int j = 0; j < 8; j++) x_lds[rr][j0 + j] = b2f(a[j]);
        } else {
            const float* sp = (const float*)src;
#pragma unroll
            for (int j = 0; j < 8; j++) x_lds[rr][j0 + j] = sp[base + j];
        }
        __syncthreads();
        if (bf) {
            const unsigned short* ik = (const unsigned short*)igk;
            const unsigned short* fk = (const unsigned short*)fgk;
#pragma unroll 8
            for (int j = 0; j < 64; j++) {
                float x = x_lds[sl][j];
                int wi = (gd0 + j) * NHEAD + hh;
                accI += x * b2f(ik[wi]);
                accF += x * b2f(fk[wi]);
            }
        } else {
            const float* ik = (const float*)igk;
            const float* fk = (const float*)fgk;
#pragma unroll 8
            for (int j = 0; j < 64; j++) {
                float x = x_lds[sl][j];
                int wi = (gd0 + j) * NHEAD + hh;
                accI += x * ik[wi];
                accF += x * fk[wi];
            }
        }
    }
    atomicAdd(&ipre[hh * SEQ + s0 + sl], accI);
    atomicAdd(&fpre[hh * SEQ + s0 + sl], accF);
}

// ---------------- per-head scans: cum(log_sigmoid(f)), a = i - cum, prefix-max
__global__ __launch_bounds__(256) void k_scan(const float* ipre, const float* fpre,
                                              const void* ib_, const void* fb_,
                                              const int* flag,
                                              float* a_g, float* amax_g, float* nfl_g) {
    __shared__ float sarr[256];
    int bf = *(volatile const int*)flag;
    int h = blockIdx.x, tid = threadIdx.x;
    float ib = bf ? b2f(((const unsigned short*)ib_)[h]) : ((const float*)ib_)[h];
    float fb = bf ? b2f(((const unsigned short*)fb_)[h]) : ((const float*)fb_)[h];
    int s0 = tid * 8;
    float lf[8], ip[8];
#pragma unroll
    for (int j = 0; j < 8; j++) {
        float fp = fpre[h * SEQ + s0 + j] + fb;
        lf[j] = fminf(fp, 0.0f) - log1pf(__expf(-fabsf(fp)));
        ip[j] = ipre[h * SEQ + s0 + j] + ib;
    }
    float cs[8]; float t = 0.f;
#pragma unroll
    for (int j = 0; j < 8; j++) { t += lf[j]; cs[j] = t; }
    sarr[tid] = t; __syncthreads();
    for (int ofs = 1; ofs < 256; ofs <<= 1) {
        float val = sarr[tid];
        if (tid >= ofs) val += sarr[tid - ofs];
        __syncthreads(); sarr[tid] = val; __syncthreads();
    }
    float excl = (tid > 0) ? sarr[tid - 1] : 0.0f;
    float cum[8], av[8];
#pragma unroll
    for (int j = 0; j < 8; j++) { cum[j] = excl + cs[j]; av[j] = ip[j] - cum[j]; }
    float mx = av[0];
#pragma unroll
    for (int j = 1; j < 8; j++) mx = fmaxf(mx, av[j]);
    __syncthreads(); sarr[tid] = mx; __syncthreads();
    for (int ofs = 1; ofs < 256; ofs <<= 1) {
        float val = sarr[tid];
        if (tid >= ofs) val = fmaxf(val, sarr[tid - ofs]);
        __syncthreads(); sarr[tid] = val; __syncthreads();
    }
    float run = (tid > 0) ? sarr[tid - 1] : -3.0e38f;
#pragma unroll
    for (int j = 0; j < 8; j++) {
        run = fmaxf(run, av[j]);
        int s = s0 + j;
        a_g[h * SEQ + s]    = av[j];
        amax_g[h * SEQ + s] = run;
        float m = cum[j] + run;
        nfl_g[h * SEQ + s]  = __expf(fminf(fmaxf(-m, -60.f), 60.f));
    }
}

// --------------------------------------------------------------- main kernel
// grid (8 heads, 64 t-tiles of 32 rows). Bs=32. mfma 16x16x32 f16.
// P carried as fp16 hi/lo pair -> PV effectively f32-accurate.
__global__ __launch_bounds__(256) void k_main(const unsigned short* __restrict__ qb,
                                              const unsigned short* __restrict__ kb,
                                              const unsigned short* __restrict__ vT,
                                              const float* __restrict__ a_g,
                                              const float* __restrict__ amax_g,
                                              const float* __restrict__ nfl_g,
                                              const float* __restrict__ gw,
                                              const int* flag, void* out) {
    __shared__ __align__(16) unsigned short q_lds[32][264];
    __shared__ __align__(16) unsigned short k_lds[32][264];
    __shared__ __align__(16) unsigned short vT_lds[272][40];   // rows 256..271: ones/zeros
    __shared__ __align__(16) unsigned short P_lds[32][40];
    __shared__ __align__(16) unsigned short Plo_lds[32][40];
    __shared__ float a_s[32], amax_t[32], nfl_t[32], rs_lds[32];
    __shared__ float mu_lds[32], var_lds[32], scale_lds[32], gw_lds[256];

    const int h   = blockIdx.x;
    const int p   = blockIdx.y;
    const int tile = (p < 32) ? 2 * p : 127 - 2 * p;  // pair heavy+light tiles
    const int t0  = tile * 32;
    const int tid = threadIdx.x;
    const int lane = tid & 63;
    const int w   = tid >> 6;          // wave 0..3
    const int l15 = lane & 15;
    const int qd  = (lane >> 4) & 3;   // quad
    const int hd0 = h * DHEAD;
    const int bf  = *(volatile const int*)flag;

    // stage q tile (once)
    {
        int row = tid >> 3, c0 = (tid & 7) * 32;
        const unsigned short* src = qb + (size_t)(t0 + row) * DMODEL + hd0 + c0;
#pragma unroll
        for (int i = 0; i < 4; i++)
            *(v8u*)&q_lds[row][c0 + i * 8] = *(const v8u*)(src + i * 8);
    }
    if (tid < 32) {
        amax_t[tid] = amax_g[h * SEQ + t0 + tid];
        nfl_t[tid]  = nfl_g[h * SEQ + t0 + tid];
        mu_lds[tid] = 0.f; var_lds[tid] = 0.f;
    }
    gw_lds[tid] = gw[hd0 + tid];
    for (int i = tid; i < 16 * 40; i += 256) {
        int r2 = i / 40, c2 = i % 40;
        vT_lds[256 + r2][c2] = (r2 == 0 && c2 < 32) ? (unsigned short)0x3C00 : (unsigned short)0;
    }

    const v4f vzero = {0.f, 0.f, 0.f, 0.f};
    v4f acc[2][4];
    v4f accN[2];
#pragma unroll
    for (int m = 0; m < 2; m++) {
        accN[m] = vzero;
#pragma unroll
        for (int n = 0; n < 4; n++) acc[m][n] = vzero;
    }

    const int mw = w >> 1, nw = w & 1;

    for (int js = 0; js <= tile; ++js) {
        const int s0 = js * 32;
        __syncthreads();   // prev iter consumed k/vT/P
        {
            int row = tid >> 3, c0 = (tid & 7) * 32;
            const unsigned short* src = kb + (size_t)(s0 + row) * DMODEL + hd0 + c0;
#pragma unroll
            for (int i = 0; i < 4; i++)
                *(v8u*)&k_lds[row][c0 + i * 8] = *(const v8u*)(src + i * 8);
        }
        {
            const unsigned short* src = vT + ((size_t)(hd0 + tid)) * SEQ + s0;
#pragma unroll
            for (int i = 0; i < 4; i++)
                *(v8u*)&vT_lds[tid][i * 8] = *(const v8u*)(src + i * 8);
        }
        if (tid < 32) a_s[tid] = a_g[h * SEQ + s0 + tid];
        __syncthreads();

        // QK^T: each wave computes one 16x16 tile of P (mw,nw)
        v4f c = vzero;
#pragma unroll
        for (int d0 = 0; d0 < 256; d0 += 32) {
            v8h a = *(const v8h*)&q_lds[mw * 16 + l15][d0 + qd * 8];
            v8h b = *(const v8h*)&k_lds[nw * 16 + l15][d0 + qd * 8];
            c = __builtin_amdgcn_mfma_f32_16x16x32_f16(a, b, c, 0, 0, 0);
        }
        // decay weights + causal mask; write P as fp16 hi + lo residual
        {
            const bool diag = (js == tile);
            const int col = nw * 16 + l15;
            const float av = a_s[col];
#pragma unroll
            for (int r = 0; r < 4; r++) {
                int row = mw * 16 + qd * 4 + r;
                float arg = fminf(av - amax_t[row], 0.0f);
                float val = c[r] * 0.0625f * __expf(arg);   // 1/sqrt(256) folded here
                if (diag && col > row) val = 0.0f;
                unsigned short hi = f2h(val);
                float lo = val - h2f(hi);
                P_lds[row][col]   = hi;
                Plo_lds[row][col] = f2h(lo);
            }
        }
        __syncthreads();

        // P @ V (hi + lo): wave w owns output cols [w*64, w*64+64)
        v8h aH0 = *(const v8h*)&P_lds[l15][qd * 8];
        v8h aH1 = *(const v8h*)&P_lds[16 + l15][qd * 8];
        v8h aL0 = *(const v8h*)&Plo_lds[l15][qd * 8];
        v8h aL1 = *(const v8h*)&Plo_lds[16 + l15][qd * 8];
#pragma unroll
        for (int nn = 0; nn < 4; nn++) {
            v8h bV = *(const v8h*)&vT_lds[w * 64 + nn * 16 + l15][qd * 8];
            acc[0][nn] = __builtin_amdgcn_mfma_f32_16x16x32_f16(aH0, bV, acc[0][nn], 0, 0, 0);
            acc[0][nn] = __builtin_amdgcn_mfma_f32_16x16x32_f16(aL0, bV, acc[0][nn], 0, 0, 0);
            acc[1][nn] = __builtin_amdgcn_mfma_f32_16x16x32_f16(aH1, bV, acc[1][nn], 0, 0, 0);
            acc[1][nn] = __builtin_amdgcn_mfma_f32_16x16x32_f16(aL1, bV, acc[1][nn], 0, 0, 0);
        }
        if (w == 3) {   // ones-column trick: row normalizer (hi+lo)
            v8h bN = *(const v8h*)&vT_lds[256 + l15][qd * 8];
            accN[0] = __builtin_amdgcn_mfma_f32_16x16x32_f16(aH0, bN, accN[0], 0, 0, 0);
            accN[0] = __builtin_amdgcn_mfma_f32_16x16x32_f16(aL0, bN, accN[0], 0, 0, 0);
            accN[1] = __builtin_amdgcn_mfma_f32_16x16x32_f16(aH1, bN, accN[1], 0, 0, 0);
            accN[1] = __builtin_amdgcn_mfma_f32_16x16x32_f16(aL1, bN, accN[1], 0, 0, 0);
        }
    }
    __syncthreads();

    if (w == 3 && l15 == 0) {
#pragma unroll
        for (int m = 0; m < 2; m++)
#pragma unroll
            for (int r = 0; r < 4; r++)
                rs_lds[m * 16 + qd * 4 + r] = accN[m][r];
    }
    __syncthreads();
    if (tid < 32)
        scale_lds[tid] = 1.0f / (fmaxf(fabsf(rs_lds[tid]), nfl_t[tid]) + 1e-6f);
    __syncthreads();

    // scale + cross-wave LayerNorm stats
#pragma unroll
    for (int m = 0; m < 2; m++)
#pragma unroll
        for (int r = 0; r < 4; r++) {
            int row = m * 16 + qd * 4 + r;
            float sc = scale_lds[row];
#pragma unroll
            for (int nn = 0; nn < 4; nn++) acc[m][nn][r] *= sc;
        }
#pragma unroll
    for (int m = 0; m < 2; m++) {
#pragma unroll
        for (int r = 0; r < 4; r++) {
            float sm = acc[m][0][r] + acc[m][1][r] + acc[m][2][r] + acc[m][3][r];
            float sq = acc[m][0][r] * acc[m][0][r] + acc[m][1][r] * acc[m][1][r]
                     + acc[m][2][r] * acc[m][2][r] + acc[m][3][r] * acc[m][3][r];
#pragma unroll
            for (int msk = 1; msk < 16; msk <<= 1) {
                sm += __shfl_xor(sm, msk, 64);
                sq += __shfl_xor(sq, msk, 64);
            }
            if (l15 == 0) {
                int row = m * 16 + qd * 4 + r;
                atomicAdd(&mu_lds[row], sm);
                atomicAdd(&var_lds[row], sq);
            }
        }
    }
    __syncthreads();

#pragma unroll
    for (int m = 0; m < 2; m++)
#pragma unroll
        for (int r = 0; r < 4; r++) {
            int row = m * 16 + qd * 4 + r;
            float mean = mu_lds[row] * (1.0f / 256.0f);
            float var  = fmaxf(var_lds[row] * (1.0f / 256.0f) - mean * mean, 0.0f);
            float rstd = rsqrtf(var + 1e-6f);
#pragma unroll
            for (int nn = 0; nn < 4; nn++) {
                int col = w * 64 + nn * 16 + l15;
                float o = (acc[m][nn][r] - mean) * rstd * gw_lds[col];
                size_t oi = (size_t)(t0 + row) * DMODEL + hd0 + col;
                if (bf) ((unsigned short*)out)[oi] = f2b(o);
                else    ((float*)out)[oi] = o;
            }
        }
}

// ---------------------------------------------------------------------- host
extern "C" void kernel_launch(void* const* d_in, const int* in_sizes, int n_in,
                              void* d_out, int out_size, void* d_ws, size_t ws_size,
                              hipStream_t stream) {
    const void* q   = d_in[0];
    const void* k   = d_in[1];
    const void* v   = d_in[2];
    const void* igk = d_in[3];
    const void* igb = d_in[4];
    const void* fgk = d_in[5];
    const void* fgb = d_in[6];
    const void* ow  = d_in[7];

    char* ws = (char*)d_ws;
    int*   flag   = (int*)(ws + 0);
    float* ipre   = (float*)(ws + 1024);
    float* fpre   = (float*)(ws + 1024 + 1 * 65536);
    float* a_g    = (float*)(ws + 1024 + 2 * 65536);
    float* amax_g = (float*)(ws + 1024 + 3 * 65536);
    float* nfl_g  = (float*)(ws + 1024 + 4 * 65536);
    float* gw     = (float*)(ws + 1024 + 5 * 65536);
    unsigned short* qb = (unsigned short*)(ws + 1024 + 5 * 65536 + 8192);
    unsigned short* kb = qb + (size_t)SEQ * DMODEL;
    unsigned short* vT = kb + (size_t)SEQ * DMODEL;

    hipMemsetAsync(ipre, 0, 2 * 65536, stream);
    k_detect<<<1, 256, 0, stream>>>((const unsigned short*)q, flag);
    k_cvt_qk<<<2048, 256, 0, stream>>>(q, k, flag, qb, kb);
    k_cvt_gw<<<8, 256, 0, stream>>>(ow, flag, gw);
    k_tr_v<<<dim3(32, 32), 256, 0, stream>>>(v, flag, vT);
    k_gates<<<dim3(64, 8), 256, 0, stream>>>(q, k, v, igk, fgk, flag, ipre, fpre);
    k_scan<<<8, 256, 0, stream>>>(ipre, fpre, igb, fgb, flag, a_g, amax_g, nfl_g);
    k_main<<<dim3(8, 64), 256, 0, stream>>>(qb, kb, vT, a_g, amax_g, nfl_g, gw, flag, d_out);
}